// Round 9
// baseline (3009.047 us; speedup 1.0000x reference)
//
#include <hip/hip_runtime.h>

// GRU (Flax GRUCell), B=64 T=512 D=512 H=512, fp32 in/out, fp16 MFMA compute.
//
// 4 groups x 16 batches x 32 blocks. Per-step h exchange via SENTINEL-CODED
// DATA POLLING on the sc1/agent transport (r6-r8 proven): |h|<1 strictly, so
// fp16 0x4000 (2.0) is unreachable; the poll wave reads exchange data until
// sentinel-free. 4-slot rotation; owner resets its own bytes 2 slots ahead
// (drift bound <=1 step; argument unchanged from r6, held on HW 3x).
// r9 change: slot layout is BATCH-MAJOR [16][512] fp16 so the polling wave
// reads LANE-CONTIGUOUS 256B/lane -- 16 fully-consumed cachelines per sweep
// instruction instead of 64 partial ones (r8 polls were L3 request-rate
// bound: 16B consumed per 1KB-strided line). The reader->fragment
// permutation is absorbed by the existing XOR-swizzled LDS staging. Also:
// w1 issues its first sweep BEFORE its x-GEMM (vmcnt(0)+sched_barrier(0)
// fence per rule 18), w2 resets use 8B stores.
// Block: 192 thr; w0=combine+publish, w1=poll+stage, w2=slot reset; all
// waves run both GEMM halves. 128 blocks x 124KB LDS -> 1 block/CU.

#define BSZ 64
#define TLEN 512
#define DDIM 512
#define HDIM 512
#define NGRP 4
#define PBLK 32
#define GB 16
#define SLOTB 16384   // per group-slot: 16 batches x 512 dims x 2B (batch-major)
#define GRPB 65536    // 4 slots
#define SENT32 0x40004000u
#define SENT64 0x4000400040004000ull
#define GUARD (1 << 16)

typedef _Float16 half8 __attribute__((ext_vector_type(8)));
typedef _Float16 half4v __attribute__((ext_vector_type(4)));
typedef float f32x4 __attribute__((ext_vector_type(4)));

__device__ __forceinline__ float sigmf(float v) { return 1.f / (1.f + __expf(-v)); }

// ---------------- setup: x fp32->fp16; fill exchange with sentinel
__global__ void gru_setup(const float* __restrict__ x, _Float16* __restrict__ xb,
                          unsigned* __restrict__ exch) {
  size_t gid = (size_t)blockIdx.x * blockDim.x + threadIdx.x;
  size_t stride = (size_t)gridDim.x * blockDim.x;
  const float4* x4 = (const float4*)x;
  size_t nx4 = (size_t)BSZ * TLEN * DDIM / 4;
  for (size_t i = gid; i < nx4; i += stride) {
    float4 v = x4[i];
    half4v o = {(_Float16)v.x, (_Float16)v.y, (_Float16)v.z, (_Float16)v.w};
    *(half4v*)(xb + 4 * i) = o;
  }
  for (size_t i = gid; i < (size_t)NGRP * GRPB / 4; i += stride) exch[i] = SENT32;
}

// dirty-chunk mask: dword low half == sentinel? (each 4B writer store covers
// 2 fp16 atomically, so per-dword low-half check is partial-write-safe)
__device__ __forceinline__ unsigned chk16(const half8* ah) {
  unsigned dirty = 0;
#pragma unroll
  for (int kt = 0; kt < 16; ++kt) {
    uint4 c;
    __builtin_memcpy(&c, &ah[kt], 16);
    unsigned bad = ((c.x & 0xFFFFu) == 0x4000u) | ((c.y & 0xFFFFu) == 0x4000u) |
                   ((c.z & 0xFFFFu) == 0x4000u) | ((c.w & 0xFFFFu) == 0x4000u);
    dirty |= bad << kt;
  }
  return dirty;
}

// ---------------- recurrence
__global__ __launch_bounds__(192, 1) void gru_rec(
    const _Float16* __restrict__ xb, const float* __restrict__ Wi,
    const float* __restrict__ Wh, const float* __restrict__ bi,
    const float* __restrict__ bhn, char* __restrict__ exch,
    float* __restrict__ out) {
  // LDS: weights 2x48KB + Ah staging 16KB + gate tiles 2x2x3KB = 124KB
  __shared__ _Float16 Wh_l[48 * 512];
  __shared__ _Float16 Wi_l[48 * 512];
  __shared__ _Float16 Ah_l[16 * 512];
  __shared__ float Gh_l[2][3 * 256];
  __shared__ float Gx_l[2][3 * 256];

  const int tid = threadIdx.x;
  const int lane = tid & 63;
  const int wid = tid >> 6;  // gate index; also role index
  const int g = blockIdx.x >> 5;
  const int rank = blockIdx.x & 31;
  const int c0 = rank * 16;
  char* const exg = exch + (size_t)g * GRPB;

  // --- one-time in-kernel weight transpose+convert into swizzled LDS
  // element k of row r at byte (r<<10) | (((k>>3)<<4)^((r&7)<<4)) | ((k&7)<<1)
  for (int idx = tid; idx < 48 * 512; idx += 192) {
    int k = idx / 48;
    int r = idx - k * 48;
    int gate = r >> 4, j = r & 15;
    int col = gate * 512 + c0 + j;
    int phys = (r << 10) | ((((k >> 3) << 4) ^ ((r & 7) << 4))) | ((k & 7) << 1);
    *(_Float16*)((char*)Wi_l + phys) = (_Float16)Wi[(size_t)k * 1536 + col];
    *(_Float16*)((char*)Wh_l + phys) = (_Float16)Wh[(size_t)k * 1536 + col];
  }

  // combine-lane mapping (wave0): batches {m0, m0+8}, cols {cp, cp+1}
  const int m0 = lane >> 3;       // 0..7
  const int cp = (lane & 7) * 2;  // 0,2,...,14
  float bir[2], biz[2], bin_[2], bh2[2];
#pragma unroll
  for (int u = 0; u < 2; ++u) {
    bir[u] = bi[c0 + cp + u];
    biz[u] = bi[512 + c0 + cp + u];
    bin_[u] = bi[1024 + c0 + cp + u];
    bh2[u] = bhn[c0 + cp + u];
  }
  float hreg[2][2] = {{0.f, 0.f}, {0.f, 0.f}};
  __syncthreads();  // weights staged

  const int ar = lane & 15;  // A row (batch) / B col-in-slice
  const int kg = lane >> 4;  // k-group
  const int wrow = wid * 16 + ar;
  const int mbat = g * GB + ar;
  const _Float16* const xrow = xb + (size_t)mbat * (TLEN * DDIM);
  // poll identity (wave1, raw lane): batch pb, dim-quarter pq, contiguous 256B
  const int pb = lane >> 2;       // 0..15
  const int pq = lane & 3;        // 0..3
  // LDS stage base for chunk c: (pb<<10) | ((pq*256 + c*16) ^ ((pb&7)<<4))
  const int sbase = pb << 10;
  const int sxor = (pb & 7) << 4;
  // h-GEMM read swizzle for row ar
  const int abase = ar << 10;
  const int axor = (ar & 7) << 4;

  for (int t = 0; t < TLEN; ++t) {
    half8 ah[16];
    const char* pp = exg + (t & 3) * SLOTB + lane * 256;  // lane-contiguous
    // a0. w1: issue first sweep BEFORE x-GEMM (flight hidden under it)
    if (wid == 1 && t > 0) {
      asm volatile(
          "global_load_dwordx4 %0,  %16, off sc1\n\t"
          "global_load_dwordx4 %1,  %16, off offset:16 sc1\n\t"
          "global_load_dwordx4 %2,  %16, off offset:32 sc1\n\t"
          "global_load_dwordx4 %3,  %16, off offset:48 sc1\n\t"
          "global_load_dwordx4 %4,  %16, off offset:64 sc1\n\t"
          "global_load_dwordx4 %5,  %16, off offset:80 sc1\n\t"
          "global_load_dwordx4 %6,  %16, off offset:96 sc1\n\t"
          "global_load_dwordx4 %7,  %16, off offset:112 sc1\n\t"
          "global_load_dwordx4 %8,  %16, off offset:128 sc1\n\t"
          "global_load_dwordx4 %9,  %16, off offset:144 sc1\n\t"
          "global_load_dwordx4 %10, %16, off offset:160 sc1\n\t"
          "global_load_dwordx4 %11, %16, off offset:176 sc1\n\t"
          "global_load_dwordx4 %12, %16, off offset:192 sc1\n\t"
          "global_load_dwordx4 %13, %16, off offset:208 sc1\n\t"
          "global_load_dwordx4 %14, %16, off offset:224 sc1\n\t"
          "global_load_dwordx4 %15, %16, off offset:240 sc1"
          : "=&v"(ah[0]), "=&v"(ah[1]), "=&v"(ah[2]), "=&v"(ah[3]),
            "=&v"(ah[4]), "=&v"(ah[5]), "=&v"(ah[6]), "=&v"(ah[7]),
            "=&v"(ah[8]), "=&v"(ah[9]), "=&v"(ah[10]), "=&v"(ah[11]),
            "=&v"(ah[12]), "=&v"(ah[13]), "=&v"(ah[14]), "=&v"(ah[15])
          : "v"(pp));
    }

    // a. x fragments + x-GEMM (all waves)
    half8 a_x[16];
    const half8* xs = (const half8*)(xrow + (size_t)t * DDIM);
#pragma unroll
    for (int kt = 0; kt < 16; ++kt) a_x[kt] = xs[kt * 4 + kg];
    f32x4 acc_x = {0.f, 0.f, 0.f, 0.f};
#pragma unroll
    for (int kt = 0; kt < 16; ++kt) {
      const int off = (((kt * 4 + kg) << 4) ^ axor);
      half8 b_i = *(const half8*)((const char*)Wi_l + (wrow << 10) + off);
      acc_x = __builtin_amdgcn_mfma_f32_16x16x32_f16(a_x[kt], b_i, acc_x, 0, 0, 0);
    }

    // b. w2: reset own bytes in slot t+2 (8B stores; drained at barrier1)
    if (wid == 2) {
      char* rst = exg + ((t + 2) & 3) * SLOTB;
      __hip_atomic_store(
          (unsigned long long*)(rst + pb * 1024 + c0 * 2 + pq * 8), SENT64,
          __ATOMIC_RELAXED, __HIP_MEMORY_SCOPE_AGENT);
    }

    // c. w1: finish first sweep, re-sweep until sentinel-free, stage to LDS
    if (wid == 1 && t > 0) {
      asm volatile("s_waitcnt vmcnt(0)" ::: "memory");
      __builtin_amdgcn_sched_barrier(0);  // rule 18: pin chk after the wait
      unsigned dirty = chk16(ah);
      int guard = 0;
      while (__any(dirty != 0u) && ++guard < GUARD) {  // bounded: no hang
        asm volatile(
            "global_load_dwordx4 %0,  %16, off sc1\n\t"
            "global_load_dwordx4 %1,  %16, off offset:16 sc1\n\t"
            "global_load_dwordx4 %2,  %16, off offset:32 sc1\n\t"
            "global_load_dwordx4 %3,  %16, off offset:48 sc1\n\t"
            "global_load_dwordx4 %4,  %16, off offset:64 sc1\n\t"
            "global_load_dwordx4 %5,  %16, off offset:80 sc1\n\t"
            "global_load_dwordx4 %6,  %16, off offset:96 sc1\n\t"
            "global_load_dwordx4 %7,  %16, off offset:112 sc1\n\t"
            "global_load_dwordx4 %8,  %16, off offset:128 sc1\n\t"
            "global_load_dwordx4 %9,  %16, off offset:144 sc1\n\t"
            "global_load_dwordx4 %10, %16, off offset:160 sc1\n\t"
            "global_load_dwordx4 %11, %16, off offset:176 sc1\n\t"
            "global_load_dwordx4 %12, %16, off offset:192 sc1\n\t"
            "global_load_dwordx4 %13, %16, off offset:208 sc1\n\t"
            "global_load_dwordx4 %14, %16, off offset:224 sc1\n\t"
            "global_load_dwordx4 %15, %16, off offset:240 sc1\n\t"
            "s_waitcnt vmcnt(0)"
            : "=&v"(ah[0]), "=&v"(ah[1]), "=&v"(ah[2]), "=&v"(ah[3]),
              "=&v"(ah[4]), "=&v"(ah[5]), "=&v"(ah[6]), "=&v"(ah[7]),
              "=&v"(ah[8]), "=&v"(ah[9]), "=&v"(ah[10]), "=&v"(ah[11]),
              "=&v"(ah[12]), "=&v"(ah[13]), "=&v"(ah[14]), "=&v"(ah[15])
            : "v"(pp));
        dirty = chk16(ah);
      }
      // stage: chunk c = batch pb, dims pq*128+c*8 .. +8 (swizzled)
#pragma unroll
      for (int c = 0; c < 16; ++c) {
        *(half8*)((char*)Ah_l + (sbase | ((pq * 256 + c * 16) ^ sxor))) = ah[c];
      }
    }
    __syncthreads();  // barrier1: Ah_l ready (and w2's resets drained)

    // d. h-GEMM from LDS fragments
    f32x4 acc_h = {0.f, 0.f, 0.f, 0.f};
    if (t > 0) {
#pragma unroll
      for (int kt = 0; kt < 16; ++kt) {
        half8 a_h = *(const half8*)((const char*)Ah_l +
                                    (abase | ((kt * 64 + kg * 16) ^ axor)));
        const int off = (((kt * 4 + kg) << 4) ^ axor);
        half8 b_h = *(const half8*)((const char*)Wh_l + (wrow << 10) + off);
        acc_h = __builtin_amdgcn_mfma_f32_16x16x32_f16(a_h, b_h, acc_h, 0, 0, 0);
      }
    }
    // publish gate tiles (double-buffered; D layout col=ar, row=kg*4+q)
#pragma unroll
    for (int q = 0; q < 4; ++q) {
      int row = kg * 4 + q;
      Gh_l[t & 1][wid * 256 + row * 16 + ar] = acc_h[q];
      Gx_l[t & 1][wid * 256 + row * 16 + ar] = acc_x[q];
    }
    __syncthreads();  // barrier2: gates(t) ready

    // f. combine + publish (wave 0): fire-and-forget sentinel-coded data
    if (wid == 0) {
      const float* GhT = Gh_l[t & 1];
      const float* GxT = Gx_l[t & 1];
      char* pub = exg + ((t + 1) & 3) * SLOTB;  // batch-major [16][512] fp16
      float hn2[2][2];
#pragma unroll
      for (int bsel = 0; bsel < 2; ++bsel) {
        const int m = m0 + 8 * bsel;
#pragma unroll
        for (int u = 0; u < 2; ++u) {
          const int gi_ = m * 16 + cp + u;
          float r = sigmf(GxT[gi_] + GhT[gi_] + bir[u]);
          float z = sigmf(GxT[256 + gi_] + GhT[256 + gi_] + biz[u]);
          float pren = GxT[512 + gi_] + bin_[u] + r * (GhT[512 + gi_] + bh2[u]);
          float n = 2.f / (1.f + __expf(-2.f * pren)) - 1.f;
          hn2[bsel][u] = (1.f - z) * n + z * hreg[bsel][u];
          hreg[bsel][u] = hn2[bsel][u];
        }
        _Float16 q0 = (_Float16)hn2[bsel][0], q1 = (_Float16)hn2[bsel][1];
        unsigned pu = ((unsigned)*(unsigned short*)&q1 << 16) | *(unsigned short*)&q0;
        __hip_atomic_store((unsigned*)(pub + m * 1024 + (c0 + cp) * 2), pu,
                           __ATOMIC_RELAXED, __HIP_MEMORY_SCOPE_AGENT);
      }
      // out stores after the publishes (off the critical path)
#pragma unroll
      for (int bsel = 0; bsel < 2; ++bsel) {
        const int b = g * GB + m0 + 8 * bsel;
        *(float2*)(out + ((size_t)b * TLEN + t) * HDIM + c0 + cp) =
            make_float2(hn2[bsel][0], hn2[bsel][1]);
      }
    }
  }

  // carry output: final h
  if (wid == 0) {
#pragma unroll
    for (int bsel = 0; bsel < 2; ++bsel) {
      const int b = g * GB + m0 + 8 * bsel;
      *(float2*)(out + (size_t)BSZ * TLEN * HDIM + (size_t)b * HDIM + c0 + cp) =
          make_float2(hreg[bsel][0], hreg[bsel][1]);
    }
  }
}

extern "C" void kernel_launch(void* const* d_in, const int* in_sizes, int n_in,
                              void* d_out, int out_size, void* d_ws, size_t ws_size,
                              hipStream_t stream) {
  const float* x = (const float*)d_in[0];
  const float* Wi = (const float*)d_in[1];
  const float* bi = (const float*)d_in[2];
  const float* Wh = (const float*)d_in[3];
  const float* bhn = (const float*)d_in[4];
  float* out = (float*)d_out;

  // ws layout (bytes): xb 33554432 | exch 262144  (total 33.8MB, proven-safe)
  char* ws = (char*)d_ws;
  _Float16* xb = (_Float16*)ws;
  char* exch = ws + 33554432;

  gru_setup<<<4096, 256, 0, stream>>>(x, xb, (unsigned*)exch);
  gru_rec<<<NGRP * PBLK, 192, 0, stream>>>(xb, Wi, Wh, bi, bhn, exch, out);
}

// Round 10
// 1987.804 us; speedup vs baseline: 1.5138x; 1.5138x over previous
//
#include <hip/hip_runtime.h>

// GRU (Flax GRUCell), B=64 T=512 D=512 H=512, fp32 in/out, fp16 MFMA compute.
//
// 4 groups x 16 batches x 32 blocks. Per-step h exchange via SENTINEL-CODED
// DATA POLLING on the sc1/agent transport (r6-r8 proven; r9's batch-major
// layout REVERTED -- r8's rank-major layout is already perfectly coalesced:
// each sweep instruction reads a contiguous 1KB window = 16 full lines).
// r10 change: INCREMENTAL CONSUMPTION. Sweep chunk kt (ranks 2kt,2kt+1)
// feeds exactly one h-MFMA, so each gate wave MFMAs chunks the moment they
// turn sentinel-free and re-polls ONLY dirty chunks (pipelined, one vmcnt).
// The h-GEMM overlaps the wait; post-discovery critical path shrinks to
// ~1 MFMA + gate store + barrier + combine. No LDS staging, one barrier.
// 4-slot rotation, owner resets own region 2 slots ahead (r6-r8 invariant,
// publish-after-barrier drain orders reset<publish; held on HW 3x).
// Poll loops bounded -> never a hang.
// Block: 192 thr; wave w = gate w; w0 combines+publishes, w1 resets.
// 128 blocks x 108KB LDS -> 1 block/CU, all co-resident.

#define BSZ 64
#define TLEN 512
#define DDIM 512
#define HDIM 512
#define NGRP 4
#define PBLK 32
#define GB 16
#define SLOTB 16384   // bytes per slot per group: 32 ranks * 512B
#define GRPB 65536    // 4 slots
#define SENT32 0x40004000u
#define GUARD (1 << 16)

typedef _Float16 half8 __attribute__((ext_vector_type(8)));
typedef _Float16 half4v __attribute__((ext_vector_type(4)));
typedef float f32x4 __attribute__((ext_vector_type(4)));

__device__ __forceinline__ float sigmf(float v) { return 1.f / (1.f + __expf(-v)); }

// ---------------- setup: x fp32->fp16; fill exchange with sentinel
__global__ void gru_setup(const float* __restrict__ x, _Float16* __restrict__ xb,
                          unsigned* __restrict__ exch) {
  size_t gid = (size_t)blockIdx.x * blockDim.x + threadIdx.x;
  size_t stride = (size_t)gridDim.x * blockDim.x;
  const float4* x4 = (const float4*)x;
  size_t nx4 = (size_t)BSZ * TLEN * DDIM / 4;
  for (size_t i = gid; i < nx4; i += stride) {
    float4 v = x4[i];
    half4v o = {(_Float16)v.x, (_Float16)v.y, (_Float16)v.z, (_Float16)v.w};
    *(half4v*)(xb + 4 * i) = o;
  }
  for (size_t i = gid; i < (size_t)NGRP * GRPB / 4; i += stride) exch[i] = SENT32;
}

// per-lane dirty mask: dword low half == sentinel? (4B writer stores cover
// 2 fp16 atomically -> per-dword low-half check is partial-write-safe)
__device__ __forceinline__ unsigned chk16(const half8* ah) {
  unsigned dirty = 0;
#pragma unroll
  for (int kt = 0; kt < 16; ++kt) {
    uint4 c;
    __builtin_memcpy(&c, &ah[kt], 16);
    unsigned bad = ((c.x & 0xFFFFu) == 0x4000u) | ((c.y & 0xFFFFu) == 0x4000u) |
                   ((c.z & 0xFFFFu) == 0x4000u) | ((c.w & 0xFFFFu) == 0x4000u);
    dirty |= bad << kt;
  }
  return dirty;
}

// ---------------- recurrence
__global__ __launch_bounds__(192, 1) void gru_rec(
    const _Float16* __restrict__ xb, const float* __restrict__ Wi,
    const float* __restrict__ Wh, const float* __restrict__ bi,
    const float* __restrict__ bhn, char* __restrict__ exch,
    float* __restrict__ out) {
  // LDS: weights 2x48KB + gate tiles 2x2x3KB = 108KB -> 1 block/CU
  __shared__ _Float16 Wh_l[48 * 512];
  __shared__ _Float16 Wi_l[48 * 512];
  __shared__ float Gh_l[2][3 * 256];
  __shared__ float Gx_l[2][3 * 256];

  const int tid = threadIdx.x;
  const int lane = tid & 63;
  const int wid = tid >> 6;  // gate index; w1 also resets
  const int g = blockIdx.x >> 5;
  const int rank = blockIdx.x & 31;
  const int c0 = rank * 16;
  char* const exg = exch + (size_t)g * GRPB;

  // --- one-time in-kernel weight transpose+convert into swizzled LDS
  // element k of row r at byte (r<<10) | (((k>>3)<<4)^((r&7)<<4)) | ((k&7)<<1)
  for (int idx = tid; idx < 48 * 512; idx += 192) {
    int k = idx / 48;
    int r = idx - k * 48;
    int gate = r >> 4, j = r & 15;
    int col = gate * 512 + c0 + j;
    int phys = (r << 10) | ((((k >> 3) << 4) ^ ((r & 7) << 4))) | ((k & 7) << 1);
    *(_Float16*)((char*)Wi_l + phys) = (_Float16)Wi[(size_t)k * 1536 + col];
    *(_Float16*)((char*)Wh_l + phys) = (_Float16)Wh[(size_t)k * 1536 + col];
  }

  // combine-lane mapping (wave0): batches {m0, m0+8}, cols {cp, cp+1}
  const int m0 = lane >> 3;       // 0..7
  const int cp = (lane & 7) * 2;  // 0,2,...,14
  float bir[2], biz[2], bin_[2], bh2[2];
#pragma unroll
  for (int u = 0; u < 2; ++u) {
    bir[u] = bi[c0 + cp + u];
    biz[u] = bi[512 + c0 + cp + u];
    bin_[u] = bi[1024 + c0 + cp + u];
    bh2[u] = bhn[c0 + cp + u];
  }
  float hreg[2][2] = {{0.f, 0.f}, {0.f, 0.f}};
  __syncthreads();  // weights staged

  const int ar = lane & 15;  // A row (batch) / B col-in-slice
  const int kg = lane >> 4;  // k-group
  const int wrow = wid * 16 + ar;
  const int axor = (ar & 7) << 4;
  const int mbat = g * GB + ar;
  const _Float16* const xrow = xb + (size_t)mbat * (TLEN * DDIM);
  // exchange chunk kt for lane (ar,kg): hbase + slot*SLOTB + kt*1024
  // (wave-contiguous 1KB window per kt; chunk kt = ranks {2kt,2kt+1})
  char* const hbase = exg + ((kg >> 1) * 512 + ar * 32 + (kg & 1) * 16);

  for (int t = 0; t < TLEN; ++t) {
    // 0. w1: reset own region in slot t+2 (fire-and-forget; drained by this
    //    wave's vmcnt(0) at the step barrier BEFORE w0's next publishes)
    if (wid == 1) {
      unsigned* rst = (unsigned*)(exg + ((t + 2) & 3) * SLOTB + rank * 512);
      __hip_atomic_store(rst + lane, SENT32, __ATOMIC_RELAXED, __HIP_MEMORY_SCOPE_AGENT);
      __hip_atomic_store(rst + 64 + lane, SENT32, __ATOMIC_RELAXED,
                         __HIP_MEMORY_SCOPE_AGENT);
    }

    // 1. x fragments + x-GEMM (overlaps other blocks' publish+visibility)
    half8 a_x[16];
    const half8* xs = (const half8*)(xrow + (size_t)t * DDIM);
#pragma unroll
    for (int kt = 0; kt < 16; ++kt) a_x[kt] = xs[kt * 4 + kg];
    f32x4 acc_x = {0.f, 0.f, 0.f, 0.f};
#pragma unroll
    for (int kt = 0; kt < 16; ++kt) {
      const int off = (((kt * 4 + kg) << 4) ^ axor);
      half8 b_i = *(const half8*)((const char*)Wi_l + (wrow << 10) + off);
      acc_x = __builtin_amdgcn_mfma_f32_16x16x32_f16(a_x[kt], b_i, acc_x, 0, 0, 0);
    }

    // 2. h: incremental poll-and-MFMA from slot t&3 (skip t=0: h=0)
    f32x4 acc_h = {0.f, 0.f, 0.f, 0.f};
    if (t > 0) {
      char* hb = hbase + (t & 3) * SLOTB;
      const char* p0 = hb;
      const char* p1 = hb + 4096;
      const char* p2 = hb + 8192;
      const char* p3 = hb + 12288;
      half8 ah[16];
      // first full sweep: 16 loads, one vmcnt (r7-proven form)
      asm volatile(
          "global_load_dwordx4 %0,  %16, off sc1\n\t"
          "global_load_dwordx4 %1,  %16, off offset:1024 sc1\n\t"
          "global_load_dwordx4 %2,  %16, off offset:2048 sc1\n\t"
          "global_load_dwordx4 %3,  %16, off offset:3072 sc1\n\t"
          "global_load_dwordx4 %4,  %17, off sc1\n\t"
          "global_load_dwordx4 %5,  %17, off offset:1024 sc1\n\t"
          "global_load_dwordx4 %6,  %17, off offset:2048 sc1\n\t"
          "global_load_dwordx4 %7,  %17, off offset:3072 sc1\n\t"
          "global_load_dwordx4 %8,  %18, off sc1\n\t"
          "global_load_dwordx4 %9,  %18, off offset:1024 sc1\n\t"
          "global_load_dwordx4 %10, %18, off offset:2048 sc1\n\t"
          "global_load_dwordx4 %11, %18, off offset:3072 sc1\n\t"
          "global_load_dwordx4 %12, %19, off sc1\n\t"
          "global_load_dwordx4 %13, %19, off offset:1024 sc1\n\t"
          "global_load_dwordx4 %14, %19, off offset:2048 sc1\n\t"
          "global_load_dwordx4 %15, %19, off offset:3072 sc1\n\t"
          "s_waitcnt vmcnt(0)"
          : "=&v"(ah[0]), "=&v"(ah[1]), "=&v"(ah[2]), "=&v"(ah[3]),
            "=&v"(ah[4]), "=&v"(ah[5]), "=&v"(ah[6]), "=&v"(ah[7]),
            "=&v"(ah[8]), "=&v"(ah[9]), "=&v"(ah[10]), "=&v"(ah[11]),
            "=&v"(ah[12]), "=&v"(ah[13]), "=&v"(ah[14]), "=&v"(ah[15])
          : "v"(p0), "v"(p1), "v"(p2), "v"(p3));
      __builtin_amdgcn_sched_barrier(0);  // rule 18: check after the wait

      unsigned consumed = 0;
      int guard = 0;
      while (true) {
        const unsigned dirty = chk16(ah);  // per-lane
        unsigned rdy = 0;
#pragma unroll
        for (int kt = 0; kt < 16; ++kt)
          if (__all(((dirty >> kt) & 1u) == 0u)) rdy |= 1u << kt;
        const unsigned newly = rdy & ~consumed;
        // MFMA newly-ready chunks (kt literal -> ah stays in registers)
#pragma unroll
        for (int kt = 0; kt < 16; ++kt) {
          if (newly & (1u << kt)) {
            const int off = (((kt * 4 + kg) << 4) ^ axor);
            half8 b_h = *(const half8*)((const char*)Wh_l + (wrow << 10) + off);
            acc_h = __builtin_amdgcn_mfma_f32_16x16x32_f16(ah[kt], b_h, acc_h, 0, 0, 0);
          }
        }
        consumed |= newly;
        if (consumed == 0xFFFFu || ++guard >= GUARD) break;  // bounded: no hang
        // re-issue ONLY not-ready chunks, pipelined, one vmcnt
        const unsigned cd = 0xFFFFu & ~rdy;
#pragma unroll
        for (int kt = 0; kt < 16; ++kt) {
          if (cd & (1u << kt)) {
            asm volatile("global_load_dwordx4 %0, %1, off sc1"
                         : "=&v"(ah[kt])
                         : "v"(hb + kt * 1024));
          }
        }
        asm volatile("s_waitcnt vmcnt(0)" ::: "memory");
        __builtin_amdgcn_sched_barrier(0);  // rule 18
      }
    }

    // 3. publish gate tiles (double-buffered; D layout col=ar, row=kg*4+q)
#pragma unroll
    for (int q = 0; q < 4; ++q) {
      int row = kg * 4 + q;
      Gh_l[t & 1][wid * 256 + row * 16 + ar] = acc_h[q];
      Gx_l[t & 1][wid * 256 + row * 16 + ar] = acc_x[q];
    }
    __syncthreads();  // gates(t) ready; drains w1's resets before w0 publishes

    // 4. combine + publish (wave 0): fire-and-forget sentinel-coded data
    if (wid == 0) {
      const float* GhT = Gh_l[t & 1];
      const float* GxT = Gx_l[t & 1];
      char* pub = exg + ((t + 1) & 3) * SLOTB + rank * 512;
      float hn2[2][2];
#pragma unroll
      for (int bsel = 0; bsel < 2; ++bsel) {
        const int m = m0 + 8 * bsel;
#pragma unroll
        for (int u = 0; u < 2; ++u) {
          const int gi_ = m * 16 + cp + u;
          float r = sigmf(GxT[gi_] + GhT[gi_] + bir[u]);
          float z = sigmf(GxT[256 + gi_] + GhT[256 + gi_] + biz[u]);
          float pren = GxT[512 + gi_] + bin_[u] + r * (GhT[512 + gi_] + bh2[u]);
          float n = 2.f / (1.f + __expf(-2.f * pren)) - 1.f;
          hn2[bsel][u] = (1.f - z) * n + z * hreg[bsel][u];
          hreg[bsel][u] = hn2[bsel][u];
        }
        _Float16 q0 = (_Float16)hn2[bsel][0], q1 = (_Float16)hn2[bsel][1];
        unsigned pu = ((unsigned)*(unsigned short*)&q1 << 16) | *(unsigned short*)&q0;
        __hip_atomic_store((unsigned*)(pub + m * 32 + cp * 2), pu, __ATOMIC_RELAXED,
                           __HIP_MEMORY_SCOPE_AGENT);
      }
      // out stores after the publishes (off the critical path)
#pragma unroll
      for (int bsel = 0; bsel < 2; ++bsel) {
        const int b = g * GB + m0 + 8 * bsel;
        *(float2*)(out + ((size_t)b * TLEN + t) * HDIM + c0 + cp) =
            make_float2(hn2[bsel][0], hn2[bsel][1]);
      }
    }
  }

  // carry output: final h
  if (wid == 0) {
#pragma unroll
    for (int bsel = 0; bsel < 2; ++bsel) {
      const int b = g * GB + m0 + 8 * bsel;
      *(float2*)(out + (size_t)BSZ * TLEN * HDIM + (size_t)b * HDIM + c0 + cp) =
          make_float2(hreg[bsel][0], hreg[bsel][1]);
    }
  }
}

extern "C" void kernel_launch(void* const* d_in, const int* in_sizes, int n_in,
                              void* d_out, int out_size, void* d_ws, size_t ws_size,
                              hipStream_t stream) {
  const float* x = (const float*)d_in[0];
  const float* Wi = (const float*)d_in[1];
  const float* bi = (const float*)d_in[2];
  const float* Wh = (const float*)d_in[3];
  const float* bhn = (const float*)d_in[4];
  float* out = (float*)d_out;

  // ws layout (bytes): xb 33554432 | exch 262144  (total 33.8MB, proven-safe)
  char* ws = (char*)d_ws;
  _Float16* xb = (_Float16*)ws;
  char* exch = ws + 33554432;

  gru_setup<<<4096, 256, 0, stream>>>(x, xb, (unsigned*)exch);
  gru_rec<<<NGRP * PBLK, 192, 0, stream>>>(xb, Wi, Wh, bi, bhn, exch, out);
}